// Round 5
// baseline (124.969 us; speedup 1.0000x reference)
//
#include <hip/hip_runtime.h>

typedef short bf16x8 __attribute__((ext_vector_type(8)));
typedef float f32x4  __attribute__((ext_vector_type(4)));

#define L_RES 1280
#define A_ATM 14
#define K_NB  30
#define FEAT  656
#define NKB   21           // K-blocks of 32 (672 padded)
#define NCH   128
#define FRAG  512          // ushorts per (tile, kb) fragment block: 64 lanes x 8
#define EPS   132          // Epre fp32 row stride: 4*132 % 32 = 16 -> 2-way max (free)
#define E_OUT_OFF (L_RES * K_NB * NCH)
#define NEDGE (L_RES * K_NB)   // 38400

// fp32 -> bf16 round-to-nearest-even
__device__ __forceinline__ ushort f2bf(float x) {
    union { float f; unsigned u; } v; v.f = x;
    unsigned r = (v.u + 0x7fffu + ((v.u >> 16) & 1u)) >> 16;
    return (ushort)r;
}

// ---------------------------------------------------------------------------
// Kernel A: per-residue features written straight to global in MFMA A-fragment
// order:  Apack[((i*2+mt)*NKB + kb)*512 + (quad*16 + frow)*8 + j]
//         = bf16( A[row = mt*16+frow][k = kb*32 + quad*8 + j] )
// Folded extra work: blocks 0..41 pack W_edge -> Wpack (same fragment order for
// B); blocks 42..191 write the E_idx float passthrough.
// ---------------------------------------------------------------------------
__global__ __launch_bounds__(256) void feature_kernel(
    const float* __restrict__ X,
    const int*   __restrict__ ridx,
    const int*   __restrict__ clab,
    const int*   __restrict__ Eidx,
    const float* __restrict__ Wpos,
    const float* __restrict__ bpos,
    const float* __restrict__ Wedge,
    ushort* __restrict__ Wpack,
    ushort* __restrict__ Apack,
    float*  __restrict__ out)
{
    __shared__ float bbs[4][3];
    __shared__ float scj[K_NB][10][3];
    __shared__ int   nbr[K_NB];

    const int i = blockIdx.x;          // residue
    const int t = threadIdx.x;

    // ---- folded: W_edge -> Wpack (fragment order), blocks 0..41 ----
    if (i < 42) {
        int u = i * 256 + t;           // one ushort8 chunk each, 84*128 total
        if (u < 84 * 128) {
            int kbq = u >> 7, n = u & 127;
            int kb = kbq >> 2, quad = kbq & 3;
            ushort val[8];
#pragma unroll
            for (int j = 0; j < 8; j++) {
                int k = kb * 32 + quad * 8 + j;
                val[j] = (k < FEAT) ? f2bf(Wedge[k * NCH + n]) : (ushort)0;
            }
            ushort* dst = Wpack + (size_t)((((n >> 4) * NKB + kb) * 64 +
                                            quad * 16 + (n & 15)) * 8);
            *(ulonglong2*)dst = *(const ulonglong2*)val;
        }
    } else if (i < 192) {
        // ---- folded: E_idx passthrough, blocks 42..191 (150*256 = 38400) ----
        int gid = (i - 42) * 256 + t;
        out[E_OUT_OFF + gid] = (float)Eidx[gid];
    }

    if (t < 12) {
        const int perm[4] = {1, 0, 2, 3};
        int a = t / 3, c = t - a * 3;
        bbs[a][c] = X[(i * A_ATM + perm[a]) * 3 + c];
    }
    if (t < K_NB) nbr[t] = Eidx[i * K_NB + t];
    __syncthreads();

    // neighbor sidechain gather (needs nbr)
    for (int idx = t; idx < K_NB * 30; idx += 256) {
        int e = idx / 30;
        int r = idx - e * 30;
        int a = r / 3, c = r - a * 3;
        scj[e][a][c] = X[(nbr[e] * A_ATM + 4 + a) * 3 + c];
    }

    ushort* Ab = Apack + (size_t)(i * 2 * NKB) * FRAG;   // base, mt=0

    // ---- positional features: kb=0, quads 0,1 ----  (60 items: e x q)
    if (t < 60) {
        int e = t >> 1, q = t & 1;
        int mt = e >> 4, f = e & 15;
        int j = nbr[e];
        int d;
        if (clab[i] == clab[j]) {
            int off = ridx[i] - ridx[j] + 32;
            d = off < 0 ? 0 : (off > 64 ? 64 : off);
        } else {
            d = 65;
        }
        ushort v[8];
#pragma unroll
        for (int jj = 0; jj < 8; jj++) {
            int c = q * 8 + jj;
            v[jj] = f2bf(Wpos[d * 16 + c] + bpos[c]);
        }
        ushort* dst = Ab + (size_t)(mt * NKB) * FRAG + (q * 16 + f) * 8;
        *(ulonglong2*)dst = *(const ulonglong2*)v;
    }
    // ---- zero pad rows 30,31 (mt=1, frow 14,15) across all kb,quad ----
    {
        const ulonglong2 z = {0ull, 0ull};
        for (int idx = t; idx < 168; idx += 256) {
            int f = 14 + (idx & 1);
            int kq = idx >> 1;                 // 0..83
            int kb = kq >> 2, q = kq & 3;
            *(ulonglong2*)(Ab + (size_t)(NKB + kb) * FRAG + (q * 16 + f) * 8) = z;
        }
        // ---- zero k-pad: kb=20, quads 2,3, all rows both mtiles ----
        if (t < 64) {
            int mt = t >> 5, q = 2 + ((t >> 4) & 1), f = t & 15;
            *(ulonglong2*)(Ab + (size_t)(mt * NKB + 20) * FRAG + (q * 16 + f) * 8) = z;
        }
    }
    __syncthreads();   // scj ready

    // ---- RBF: 40 pairs x 30 edges; each item -> two 16B fragment chunks ----
    for (int idx = t; idx < 1200; idx += 256) {
        int p = idx / 30;
        int e = idx - p * 30;          // e fastest -> coalesced 16B chunk runs
        int ab = p / 10, as = p - ab * 10;
        float dx = bbs[ab][0] - scj[e][as][0];
        float dy = bbs[ab][1] - scj[e][as][1];
        float dz = bbs[ab][2] - scj[e][as][2];
        float dist = sqrtf(dx * dx + dy * dy + dz * dz + 1e-6f);
        bool self = (nbr[e] == i);     // AUTOREGRESSIVE: zero RBF on self edges

        ushort v[16];
#pragma unroll
        for (int r = 0; r < 16; r++) {
            float mu = 2.0f + (float)r * (20.0f / 15.0f);
            float a0 = (dist - mu) * 0.8f;
            v[r] = self ? (ushort)0 : f2bf(__expf(-a0 * a0));
        }
        int mt = e >> 4, f = e & 15;
        int kb, qb;
        if (p & 1) { kb = (p + 1) >> 1; qb = 0; }
        else       { kb = p >> 1;       qb = 2; }
        ushort* dst = Ab + (size_t)(mt * NKB + kb) * FRAG + (qb * 16 + f) * 8;
        *(ulonglong2*)dst        = *(const ulonglong2*)&v[0];
        *(ulonglong2*)(dst + 128) = *(const ulonglong2*)&v[8];  // quad+1: +16 lanes*8
    }
}

// ---------------------------------------------------------------------------
// Kernel B: C[40960 x 128] = Apack @ Wpack^T, then per-edge LayerNorm.
// M=128 per block (8 m-tiles = 4 residues), 512 threads / 8 waves.
// Wave w owns n-tile w; A and B fragments stream from L2/L3 as contiguous
// per-wave 1KB loads. LDS only for the C -> LN transpose.
// ---------------------------------------------------------------------------
__global__ __launch_bounds__(512) void gemm_ln_kernel(
    const ushort* __restrict__ Wpack,
    const ushort* __restrict__ Apack,
    const float*  __restrict__ gamma,
    const float*  __restrict__ beta,
    float* __restrict__ out)
{
    __shared__ float Epre[128][EPS];   // 67,584 B -> 2 blocks/CU

    const int b = blockIdx.x;          // 0..319, rows [b*128, b*128+128)
    const int t = threadIdx.x;
    const int w = t >> 6;              // wave = n-tile
    const int lane = t & 63;
    const int frow = lane & 15;
    const int quad = lane >> 4;

    const ushort* Bp = Wpack + ((size_t)(w * NKB)) * FRAG + lane * 8;
    const ushort* Ap = Apack + ((size_t)(b * 8) * NKB) * FRAG + lane * 8;

    f32x4 acc[8];
#pragma unroll
    for (int m = 0; m < 8; m++) acc[m] = (f32x4){0.f, 0.f, 0.f, 0.f};

    bf16x8 a[8], bb;
#pragma unroll
    for (int m = 0; m < 8; m++) a[m] = *(const bf16x8*)(Ap + (size_t)(m * NKB) * FRAG);
    bb = *(const bf16x8*)(Bp);

#pragma unroll
    for (int kb = 0; kb < NKB; kb++) {
        bf16x8 ca[8] = {a[0], a[1], a[2], a[3], a[4], a[5], a[6], a[7]};
        bf16x8 cb = bb;
        if (kb + 1 < NKB) {            // depth-1 prefetch from L2/L3
#pragma unroll
            for (int m = 0; m < 8; m++)
                a[m] = *(const bf16x8*)(Ap + (size_t)(m * NKB + kb + 1) * FRAG);
            bb = *(const bf16x8*)(Bp + (size_t)(kb + 1) * FRAG);
        }
#pragma unroll
        for (int m = 0; m < 8; m++)
            acc[m] = __builtin_amdgcn_mfma_f32_16x16x32_bf16(ca[m], cb, acc[m], 0, 0, 0);
    }

    // C/D layout (m89/m91): col = lane&15, row = quad*4 + reg
#pragma unroll
    for (int m = 0; m < 8; m++)
#pragma unroll
        for (int r = 0; r < 4; r++)
            Epre[m * 16 + quad * 4 + r][w * 16 + frow] = acc[m][r];
    __syncthreads();

    const float g0 = gamma[lane], g1 = gamma[lane + 64];
    const float bt0 = beta[lane], bt1 = beta[lane + 64];

    for (int e = w; e < 128; e += 8) {
        int ed = e & 31;
        if (ed >= K_NB) continue;      // padded rows 30,31 of each residue
        float v0 = Epre[e][lane];
        float v1 = Epre[e][lane + 64];
        float s = v0 + v1;
        float q = v0 * v0 + v1 * v1;
#pragma unroll
        for (int off = 32; off > 0; off >>= 1) {
            s += __shfl_xor(s, off);
            q += __shfl_xor(q, off);
        }
        float mean = s * (1.0f / 128.0f);
        float var  = q * (1.0f / 128.0f) - mean * mean;
        float rstd = rsqrtf(var + 1e-5f);
        int res = b * 4 + (e >> 5);
        float* o = out + ((size_t)res * K_NB + ed) * NCH;
        o[lane]      = (v0 - mean) * rstd * g0 + bt0;
        o[lane + 64] = (v1 - mean) * rstd * g1 + bt1;
    }
}

extern "C" void kernel_launch(void* const* d_in, const int* in_sizes, int n_in,
                              void* d_out, int out_size, void* d_ws, size_t ws_size,
                              hipStream_t stream) {
    const float* X     = (const float*)d_in[0];
    const int*   ridx  = (const int*)  d_in[1];
    const int*   clab  = (const int*)  d_in[2];
    const int*   Eidx  = (const int*)  d_in[3];
    // d_in[4] = atom_mask (unused by reference forward)
    const float* Wpos  = (const float*)d_in[5];
    const float* bpos  = (const float*)d_in[6];
    const float* Wedge = (const float*)d_in[7];
    const float* gamma = (const float*)d_in[8];
    const float* beta  = (const float*)d_in[9];
    float* out = (float*)d_out;

    ushort* Wpack = (ushort*)d_ws;                 // 84*128*8 = 86,016 ushorts (168 KB)
    ushort* Apack = Wpack + 84 * 128 * 8;          // 2560*21*512 ushorts (~55 MB)

    feature_kernel<<<L_RES, 256, 0, stream>>>(
        X, ridx, clab, Eidx, Wpos, bpos, Wedge, Wpack, Apack, out);
    gemm_ln_kernel<<<(L_RES * 2 * 16) / 128, 512, 0, stream>>>(
        Wpack, Apack, gamma, beta, out);
}

// Round 6
// 112.453 us; speedup vs baseline: 1.1113x; 1.1113x over previous
//
#include <hip/hip_runtime.h>

typedef short bf16x8 __attribute__((ext_vector_type(8)));
typedef float f32x4  __attribute__((ext_vector_type(4)));

#define L_RES 1280
#define A_ATM 14
#define K_NB  30
#define FEAT  656
#define NKB   21           // K-blocks of 32 (672 padded)
#define NCH   128
#define FRAG  512          // ushorts per (tile, kb) fragment block: 64 lanes x 8
#define E_OUT_OFF (L_RES * K_NB * NCH)
#define NEDGE (L_RES * K_NB)

// fp32 -> bf16 round-to-nearest-even
__device__ __forceinline__ ushort f2bf(float x) {
    union { float f; unsigned u; } v; v.f = x;
    unsigned r = (v.u + 0x7fffu + ((v.u >> 16) & 1u)) >> 16;
    return (ushort)r;
}

// W_edge [656][128] fp32 -> Wpack in MFMA B-fragment order:
//   Wpack[((ntile*NKB + kb)*64 + quad*16 + (n&15))*8 + j]
//     = bf16( W[(kb*32 + quad*8 + j)*128 + ntile*16 + (n&15)] ), zero k-pad.
__global__ __launch_bounds__(256) void prep_kernel(const float* __restrict__ W,
                                                   ushort* __restrict__ Wpack) {
    int u = blockIdx.x * 256 + threadIdx.x;     // 84*128 ushort8 chunks
    if (u >= 84 * 128) return;
    int kbq = u >> 7, n = u & 127;
    int kb = kbq >> 2, quad = kbq & 3;
    ushort val[8];
#pragma unroll
    for (int j = 0; j < 8; j++) {
        int k = kb * 32 + quad * 8 + j;
        val[j] = (k < FEAT) ? f2bf(W[k * NCH + n]) : (ushort)0;
    }
    ushort* dst = Wpack + (size_t)((((n >> 4) * NKB + kb) * 64 + quad * 16 + (n & 15)) * 8);
    *(ulonglong2*)dst = *(const ulonglong2*)val;
}

// One wave = one residue. No __syncthreads anywhere.
__global__ __launch_bounds__(256) void sidechain_fused_kernel(
    const float* __restrict__ X,
    const int*   __restrict__ ridx,
    const int*   __restrict__ clab,
    const int*   __restrict__ Eidx,
    const float* __restrict__ Wpos,
    const float* __restrict__ bpos,
    const ushort* __restrict__ Wpack,
    const float* __restrict__ gamma,
    const float* __restrict__ beta,
    float* __restrict__ out)
{
    __shared__ float scj[4][K_NB][10][3];   // wave-private neighbor sidechain coords
    __shared__ float bbs[4][4][3];          // wave-private backbone atoms [1,0,2,3]

    const int t    = threadIdx.x;
    const int w    = t >> 6;
    const int lane = t & 63;
    const int i    = blockIdx.x * 4 + w;    // residue (320*4 = 1280 exactly)
    const int frow = lane & 15;
    const int quad = lane >> 4;

    // ---- wave-private staging (ordered ds ops within the wave; no barrier) ----
    if (lane < 12) {
        const int perm[4] = {1, 0, 2, 3};
        int a = lane / 3, c = lane - a * 3;
        bbs[w][a][c] = X[(i * A_ATM + perm[a]) * 3 + c];
    }
    for (int idx = lane; idx < K_NB * 30; idx += 64) {
        int e = idx / 30, r = idx - e * 30;
        int a = r / 3, c = r - a * 3;
        int j = Eidx[i * K_NB + e];
        scj[w][e][a][c] = X[(j * A_ATM + 4 + a) * 3 + c];
    }
    // E_idx passthrough (as float)
    if (lane < K_NB) out[E_OUT_OFF + i * K_NB + lane] = (float)Eidx[i * K_NB + lane];

    // ---- per-lane edge metadata: rows frow (m0) and 16+frow (m1) ----
    const int e0 = frow;
    const int e1 = 16 + frow;
    const bool v1 = (e1 < K_NB);            // rows 30,31 are zero padding
    const int j0 = Eidx[i * K_NB + e0];
    const int j1 = v1 ? Eidx[i * K_NB + e1] : 0;
    const bool rbf0 = (j0 != i);             // AUTOREGRESSIVE self-edge: RBF zeroed
    const bool rbf1 = v1 && (j1 != i);

    const int ri = ridx[i], ci = clab[i];
    int d0, d1;
    {
        int off0 = ri - ridx[j0] + 32;
        off0 = off0 < 0 ? 0 : (off0 > 64 ? 64 : off0);
        d0 = (ci == clab[j0]) ? off0 : 65;
        int off1 = ri - ridx[j1] + 32;
        off1 = off1 < 0 ? 0 : (off1 > 64 ? 64 : off1);
        d1 = (ci == clab[j1]) ? off1 : 65;
    }

    // ---- GEMM with inline A-fragment generation ----
    const ushort* Bbase = Wpack + (size_t)lane * 8;
    f32x4 acc0[8], acc1[8];
#pragma unroll
    for (int n = 0; n < 8; n++) {
        acc0[n] = (f32x4){0.f, 0.f, 0.f, 0.f};
        acc1[n] = (f32x4){0.f, 0.f, 0.f, 0.f};
    }

#pragma unroll
    for (int kb = 0; kb < NKB; kb++) {
        bf16x8 b[8];
#pragma unroll
        for (int n = 0; n < 8; n++)
            b[n] = *(const bf16x8*)(Bbase + (size_t)(n * NKB + kb) * FRAG);

        ushort u0[8], u1[8];
        if (kb == 0 && quad < 2) {
            // positional chunk: cols c = quad*8 + j
#pragma unroll
            for (int j = 0; j < 8; j++) {
                int c = quad * 8 + j;
                float bp = bpos[c];
                u0[j] = f2bf(Wpos[d0 * 16 + c] + bp);
                u1[j] = v1 ? f2bf(Wpos[d1 * 16 + c] + bp) : (ushort)0;
            }
        } else {
            // RBF half-pair: p = 2kb-1+(quad>>1), r0 = (quad&1)*8
            bool kv = !(kb == NKB - 1 && quad >= 2);   // k >= 656 -> zero
            int p  = kv ? (2 * kb - 1 + (quad >> 1)) : 0;
            int r0 = (quad & 1) * 8;
            int ab = p / 10, as = p - ab * 10;
            float bx = bbs[w][ab][0], by = bbs[w][ab][1], bz = bbs[w][ab][2];
            float x0 = scj[w][e0][as][0], y0 = scj[w][e0][as][1], z0 = scj[w][e0][as][2];
            int e1c = v1 ? e1 : 0;
            float x1 = scj[w][e1c][as][0], y1 = scj[w][e1c][as][1], z1 = scj[w][e1c][as][2];
            float dx0 = bx - x0, dy0 = by - y0, dz0 = bz - z0;
            float dx1 = bx - x1, dy1 = by - y1, dz1 = bz - z1;
            float dist0 = sqrtf(dx0 * dx0 + dy0 * dy0 + dz0 * dz0 + 1e-6f);
            float dist1 = sqrtf(dx1 * dx1 + dy1 * dy1 + dz1 * dz1 + 1e-6f);
            bool m0ok = kv && rbf0, m1ok = kv && rbf1;
#pragma unroll
            for (int j = 0; j < 8; j++) {
                float mu = 2.0f + (float)(r0 + j) * (20.0f / 15.0f);
                float t0 = (dist0 - mu) * 0.8f;
                float t1 = (dist1 - mu) * 0.8f;
                u0[j] = m0ok ? f2bf(__expf(-t0 * t0)) : (ushort)0;
                u1[j] = m1ok ? f2bf(__expf(-t1 * t1)) : (ushort)0;
            }
        }
        bf16x8 a0 = *(const bf16x8*)u0;
        bf16x8 a1 = *(const bf16x8*)u1;
#pragma unroll
        for (int n = 0; n < 8; n++)
            acc0[n] = __builtin_amdgcn_mfma_f32_16x16x32_bf16(a0, b[n], acc0[n], 0, 0, 0);
#pragma unroll
        for (int n = 0; n < 8; n++)
            acc1[n] = __builtin_amdgcn_mfma_f32_16x16x32_bf16(a1, b[n], acc1[n], 0, 0, 0);
    }

    // ---- in-register LayerNorm + store ----
    // C/D layout (m89/m91): col = ntile*16 + frow, row = mtile*16 + quad*4 + reg.
    float g[8], bt[8];
#pragma unroll
    for (int n = 0; n < 8; n++) {
        g[n]  = gamma[n * 16 + frow];
        bt[n] = beta[n * 16 + frow];
    }

#pragma unroll
    for (int m = 0; m < 2; m++) {
        f32x4* acc = m ? acc1 : acc0;
#pragma unroll
        for (int r = 0; r < 4; r++) {
            float s = 0.f, q = 0.f;
#pragma unroll
            for (int n = 0; n < 8; n++) {
                float v = acc[n][r];
                s += v; q += v * v;
            }
            // reduce across the 16-lane group holding this row (offsets 1,2,4,8)
#pragma unroll
            for (int off = 1; off < 16; off <<= 1) {
                s += __shfl_xor(s, off);
                q += __shfl_xor(q, off);
            }
            float mean = s * (1.0f / 128.0f);
            float var  = q * (1.0f / 128.0f) - mean * mean;
            float rstd = rsqrtf(var + 1e-5f);
            int edge = m * 16 + quad * 4 + r;
            if (edge < K_NB) {
                float* o = out + ((size_t)i * K_NB + edge) * NCH + frow;
#pragma unroll
                for (int n = 0; n < 8; n++)
                    o[n * 16] = (acc[n][r] - mean) * rstd * g[n] + bt[n];
            }
        }
    }
}

extern "C" void kernel_launch(void* const* d_in, const int* in_sizes, int n_in,
                              void* d_out, int out_size, void* d_ws, size_t ws_size,
                              hipStream_t stream) {
    const float* X     = (const float*)d_in[0];
    const int*   ridx  = (const int*)  d_in[1];
    const int*   clab  = (const int*)  d_in[2];
    const int*   Eidx  = (const int*)  d_in[3];
    // d_in[4] = atom_mask (unused by reference forward)
    const float* Wpos  = (const float*)d_in[5];
    const float* bpos  = (const float*)d_in[6];
    const float* Wedge = (const float*)d_in[7];
    const float* gamma = (const float*)d_in[8];
    const float* beta  = (const float*)d_in[9];
    float* out = (float*)d_out;

    ushort* Wpack = (ushort*)d_ws;   // 84*128*8 ushorts = 168 KB

    prep_kernel<<<42, 256, 0, stream>>>(Wedge, Wpack);
    sidechain_fused_kernel<<<L_RES / 4, 256, 0, stream>>>(
        X, ridx, clab, Eidx, Wpos, bpos, Wpack, gamma, beta, out);
}

// Round 7
// 110.087 us; speedup vs baseline: 1.1352x; 1.0215x over previous
//
#include <hip/hip_runtime.h>

typedef short    bf16x8 __attribute__((ext_vector_type(8)));
typedef float    f32x4  __attribute__((ext_vector_type(4)));
typedef unsigned u32x4  __attribute__((ext_vector_type(4)));

#define L_RES 1280
#define A_ATM 14
#define K_NB  30
#define FEAT  656
#define NKB   21           // K-blocks of 32 (672 padded)
#define NCH   128
#define FRAG  512          // ushorts per (tile, kb) fragment block: 64 lanes x 8
#define E_OUT_OFF (L_RES * K_NB * NCH)

// fp32 -> bf16 round-to-nearest-even (used once, in W prep)
__device__ __forceinline__ ushort f2bf(float x) {
    union { float f; unsigned u; } v; v.f = x;
    unsigned r = (v.u + 0x7fffu + ((v.u >> 16) & 1u)) >> 16;
    return (ushort)r;
}
// truncating pack of two fp32 -> packed bf16x2 (lo, hi)
__device__ __forceinline__ unsigned pkbf(float lo, float hi) {
    union { float f; unsigned u; } a, b; a.f = lo; b.f = hi;
    return (a.u >> 16) | (b.u & 0xffff0000u);
}

// W_edge [656][128] fp32 -> Wpack in MFMA B-fragment order:
//   Wpack[((ntile*NKB + kb)*64 + quad*16 + (n&15))*8 + j]
__global__ __launch_bounds__(256) void prep_kernel(const float* __restrict__ W,
                                                   ushort* __restrict__ Wpack) {
    int u = blockIdx.x * 256 + threadIdx.x;     // 84*128 ushort8 chunks
    if (u >= 84 * 128) return;
    int kbq = u >> 7, n = u & 127;
    int kb = kbq >> 2, quad = kbq & 3;
    ushort val[8];
#pragma unroll
    for (int j = 0; j < 8; j++) {
        int k = kb * 32 + quad * 8 + j;
        val[j] = (k < FEAT) ? f2bf(W[k * NCH + n]) : (ushort)0;
    }
    ushort* dst = Wpack + (size_t)((((n >> 4) * NKB + kb) * 64 + quad * 16 + (n & 15)) * 8);
    *(ulonglong2*)dst = *(const ulonglong2*)val;
}

// Block = 2 residues x 2 K-half waves. Two barriers total (staging, exchange).
__global__ __launch_bounds__(256) void sidechain_fused_kernel(
    const float* __restrict__ X,
    const int*   __restrict__ ridx,
    const int*   __restrict__ clab,
    const int*   __restrict__ Eidx,
    const float* __restrict__ Wpos,
    const float* __restrict__ bpos,
    const ushort* __restrict__ Wpack,
    const float* __restrict__ gamma,
    const float* __restrict__ beta,
    float* __restrict__ out)
{
    __shared__ __align__(16) float scj[2][K_NB][10][4];  // 9.6 KB, float4 rows
    __shared__ float bbs[2][4][3];
    __shared__ __align__(16) float xch[2][16][64][4];    // 32 KB partial-C exchange

    const int blk  = blockIdx.x;
    const int t    = threadIdx.x;
    const int w    = t >> 6;
    const int lane = t & 63;
    const int rh   = w & 1;            // residue within block
    const int kh   = w >> 1;           // K-half: 0 -> kb 0..10, 1 -> kb 11..20
    const int i    = blk * 2 + rh;
    const int frow = lane & 15;
    const int quad = lane >> 4;

    // ---- cooperative staging for both residues ----
    if (t < 24) {
        const int perm[4] = {1, 0, 2, 3};
        int r = t / 12, rr = t - r * 12, a = rr / 3, c = rr - a * 3;
        bbs[r][a][c] = X[((blk * 2 + r) * A_ATM + perm[a]) * 3 + c];
    }
#pragma unroll
    for (int idx = t; idx < 600; idx += 256) {           // 2 res x 30 edges x 10 atoms
        int r = idx / 300, rem = idx - r * 300;
        int e = rem / 10, a = rem - e * 10;
        int j = Eidx[(blk * 2 + r) * K_NB + e];
        const float* xp = X + ((size_t)j * A_ATM + 4 + a) * 3;
        float4 v = make_float4(xp[0], xp[1], xp[2], 0.f);
        *(float4*)&scj[r][e][a][0] = v;
    }
    __syncthreads();

    // ---- per-lane edge metadata (rows e0=frow, e1=16+frow of residue i) ----
    const int e0 = frow, e1 = 16 + frow;
    const bool v1 = (e1 < K_NB);
    const int j0 = Eidx[i * K_NB + e0];
    const int j1 = v1 ? Eidx[i * K_NB + e1] : 0;
    const bool ok0 = (j0 != i);                 // AUTOREGRESSIVE self-edge mask
    const bool ok1 = v1 && (j1 != i);
    int d0 = 65, d1 = 65;
    {
        int ci = clab[i], ri = ridx[i];
        if (ci == clab[j0]) { int o = ri - ridx[j0] + 32; d0 = o < 0 ? 0 : (o > 64 ? 64 : o); }
        if (ci == clab[j1]) { int o = ri - ridx[j1] + 32; d1 = o < 0 ? 0 : (o > 64 ? 64 : o); }
    }

    // ---- GEMM over this wave's kb range, inline A-fragment generation ----
    const int kb_lo = kh ? 11 : 0;
    const int kb_hi = kh ? NKB : 11;
    const ushort* Bbase = Wpack + (size_t)lane * 8;

    f32x4 acc0[8], acc1[8];
#pragma unroll
    for (int n = 0; n < 8; n++) {
        acc0[n] = (f32x4){0.f, 0.f, 0.f, 0.f};
        acc1[n] = (f32x4){0.f, 0.f, 0.f, 0.f};
    }

    const float cs = 0.96089795f;               // 0.8 * sqrt(log2 e)
    const float mustep = 1.33333333f * cs;      // (20/15) * cs
    const int   r0 = (quad & 1) * 8;
    const float mubase = (2.0f + (float)r0 * 1.33333333f) * cs;

    for (int kb = kb_lo; kb < kb_hi; kb++) {
        bf16x8 b[8];
#pragma unroll
        for (int n = 0; n < 8; n++)
            b[n] = *(const bf16x8*)(Bbase + (size_t)(n * NKB + kb) * FRAG);

        union { u32x4 u; bf16x8 h; } A0, A1;
        if (kb == 0 && quad < 2) {
            // positional chunk: cols c = quad*8 + j
            float p0[8], p1[8];
#pragma unroll
            for (int j = 0; j < 8; j++) {
                int c = quad * 8 + j;
                float bp = bpos[c];
                p0[j] = Wpos[d0 * 16 + c] + bp;
                p1[j] = v1 ? (Wpos[d1 * 16 + c] + bp) : 0.f;
            }
#pragma unroll
            for (int jj = 0; jj < 4; jj++) {
                A0.u[jj] = pkbf(p0[2 * jj], p0[2 * jj + 1]);
                A1.u[jj] = pkbf(p1[2 * jj], p1[2 * jj + 1]);
            }
        } else {
            // RBF half-pair p = 2kb-1+(quad>>1), rbf indices r0..r0+7
            bool kv = !(kb == NKB - 1 && quad >= 2);   // k >= 656 -> zero pad
            int p  = kv ? (2 * kb - 1 + (quad >> 1)) : 0;
            int ab = p / 10, as = p - ab * 10;
            float bx = bbs[rh][ab][0], by = bbs[rh][ab][1], bz = bbs[rh][ab][2];
            f32x4 s0 = *(const f32x4*)&scj[rh][e0][as][0];
            f32x4 s1 = *(const f32x4*)&scj[rh][v1 ? e1 : 0][as][0];
            float dx0 = bx - s0[0], dy0 = by - s0[1], dz0 = bz - s0[2];
            float dx1 = bx - s1[0], dy1 = by - s1[1], dz1 = bz - s1[2];
            float dd0 = sqrtf(dx0 * dx0 + dy0 * dy0 + dz0 * dz0 + 1e-6f) * cs - mubase;
            float dd1 = sqrtf(dx1 * dx1 + dy1 * dy1 + dz1 * dz1 + 1e-6f) * cs - mubase;
            bool m0 = kv && ok0, m1 = kv && ok1;
#pragma unroll
            for (int jj = 0; jj < 4; jj++) {
                float cA = (float)(2 * jj) * mustep;
                float cB = (float)(2 * jj + 1) * mustep;
                float tA0 = dd0 - cA, tB0 = dd0 - cB;
                float tA1 = dd1 - cA, tB1 = dd1 - cB;
                unsigned q0 = pkbf(exp2f(-(tA0 * tA0)), exp2f(-(tB0 * tB0)));
                unsigned q1 = pkbf(exp2f(-(tA1 * tA1)), exp2f(-(tB1 * tB1)));
                A0.u[jj] = m0 ? q0 : 0u;
                A1.u[jj] = m1 ? q1 : 0u;
            }
        }
#pragma unroll
        for (int n = 0; n < 8; n++)
            acc0[n] = __builtin_amdgcn_mfma_f32_16x16x32_bf16(A0.h, b[n], acc0[n], 0, 0, 0);
#pragma unroll
        for (int n = 0; n < 8; n++)
            acc1[n] = __builtin_amdgcn_mfma_f32_16x16x32_bf16(A1.h, b[n], acc1[n], 0, 0, 0);
    }

    // ---- combine K-halves via LDS, then in-register LN (kh0 waves) ----
    if (kh == 1) {
#pragma unroll
        for (int n = 0; n < 8; n++) {
            *(f32x4*)&xch[rh][n][lane][0]     = acc0[n];
            *(f32x4*)&xch[rh][8 + n][lane][0] = acc1[n];
        }
        if (lane < K_NB) out[E_OUT_OFF + i * K_NB + lane] = (float)Eidx[i * K_NB + lane];
    }
    __syncthreads();
    if (kh == 0) {
#pragma unroll
        for (int n = 0; n < 8; n++) {
            acc0[n] += *(const f32x4*)&xch[rh][n][lane][0];
            acc1[n] += *(const f32x4*)&xch[rh][8 + n][lane][0];
        }
        float g[8], bt[8];
#pragma unroll
        for (int n = 0; n < 8; n++) {
            g[n]  = gamma[n * 16 + frow];
            bt[n] = beta[n * 16 + frow];
        }
        // C/D layout (m89/m91): col = n*16+frow, row = mtile*16 + quad*4 + r
#pragma unroll
        for (int m = 0; m < 2; m++) {
            f32x4* acc = m ? acc1 : acc0;
#pragma unroll
            for (int r = 0; r < 4; r++) {
                float s = 0.f, q = 0.f;
#pragma unroll
                for (int n = 0; n < 8; n++) {
                    float v = acc[n][r];
                    s += v; q += v * v;
                }
#pragma unroll
                for (int off = 1; off < 16; off <<= 1) {
                    s += __shfl_xor(s, off);
                    q += __shfl_xor(q, off);
                }
                float mean = s * (1.0f / 128.0f);
                float var  = q * (1.0f / 128.0f) - mean * mean;
                float rstd = rsqrtf(var + 1e-5f);
                int edge = m * 16 + quad * 4 + r;
                if (edge < K_NB) {
                    float* o = out + ((size_t)i * K_NB + edge) * NCH + frow;
#pragma unroll
                    for (int n = 0; n < 8; n++)
                        o[n * 16] = (acc[n][r] - mean) * rstd * g[n] + bt[n];
                }
            }
        }
    }
}

extern "C" void kernel_launch(void* const* d_in, const int* in_sizes, int n_in,
                              void* d_out, int out_size, void* d_ws, size_t ws_size,
                              hipStream_t stream) {
    const float* X     = (const float*)d_in[0];
    const int*   ridx  = (const int*)  d_in[1];
    const int*   clab  = (const int*)  d_in[2];
    const int*   Eidx  = (const int*)  d_in[3];
    // d_in[4] = atom_mask (unused by reference forward)
    const float* Wpos  = (const float*)d_in[5];
    const float* bpos  = (const float*)d_in[6];
    const float* Wedge = (const float*)d_in[7];
    const float* gamma = (const float*)d_in[8];
    const float* beta  = (const float*)d_in[9];
    float* out = (float*)d_out;

    ushort* Wpack = (ushort*)d_ws;   // 84*128*8 ushorts = 168 KB

    prep_kernel<<<42, 256, 0, stream>>>(Wedge, Wpack);
    sidechain_fused_kernel<<<L_RES / 2, 256, 0, stream>>>(
        X, ridx, clab, Eidx, Wpos, bpos, Wpack, gamma, beta, out);
}